// Round 1
// baseline (476.746 us; speedup 1.0000x reference)
//
#include <hip/hip_runtime.h>
#include <hip/hip_bf16.h>

#define IN_CH 128
#define HID   64
#define N_REL 8
#define BM    64
#define BN    64

// ---------------------------------------------------------------------------
// proj: xp[r][n][h] = dot(x[n][:], W_r[h][:])  for r in 0..8
//   r < 8  -> W_rel[r], written to xp buffer
//   r == 8 -> W_self,  written to agg buffer (initializes the aggregation)
// 64x64 output tile per block, K=128 un-tiled, 4x4 micro-tile per thread.
// ---------------------------------------------------------------------------
__global__ __launch_bounds__(256) void proj_kernel(
    const float* __restrict__ x,       // [N,128]
    const float* __restrict__ W_rel,   // [8,64,128]
    const float* __restrict__ W_self,  // [64,128]
    float* __restrict__ xp,            // [8,N,64]
    float* __restrict__ agg,           // [N,64]
    int N)
{
    const int r    = blockIdx.y;                 // 0..8
    const int row0 = blockIdx.x * BM;
    const float* W = (r < N_REL) ? (W_rel + (size_t)r * HID * IN_CH) : W_self;
    float* outp    = (r < N_REL) ? (xp + (size_t)r * N * HID) : agg;

    __shared__ float As[IN_CH][BM];   // [k][node]   (transposed x tile)
    __shared__ float Bs[IN_CH][BN];   // [k][h]      (transposed W tile)

    const int tid = threadIdx.x;
    // Staging: thread handles node/row nl = tid&63, k-quarter kb=(tid>>6)*32.
    // LDS writes: lanes have distinct nl -> consecutive floats -> 2-way (free).
    const int nl = tid & 63;
    const int kb = (tid >> 6) * 32;
    const int gn = row0 + nl;
    {
        const float* xr = x + (size_t)gn * IN_CH + kb;
        #pragma unroll
        for (int j = 0; j < 8; ++j) {
            float4 v = (gn < N) ? *(const float4*)(xr + 4 * j)
                                : make_float4(0.f, 0.f, 0.f, 0.f);
            As[kb + 4*j + 0][nl] = v.x;
            As[kb + 4*j + 1][nl] = v.y;
            As[kb + 4*j + 2][nl] = v.z;
            As[kb + 4*j + 3][nl] = v.w;
        }
        const float* wr = W + (size_t)nl * IN_CH + kb;   // h = nl
        #pragma unroll
        for (int j = 0; j < 8; ++j) {
            float4 v = *(const float4*)(wr + 4 * j);
            Bs[kb + 4*j + 0][nl] = v.x;
            Bs[kb + 4*j + 1][nl] = v.y;
            Bs[kb + 4*j + 2][nl] = v.z;
            Bs[kb + 4*j + 3][nl] = v.w;
        }
    }
    __syncthreads();

    const int tx = tid & 15;   // output-col group
    const int ty = tid >> 4;   // node-row group
    float acc[4][4] = {};

    #pragma unroll 4
    for (int k = 0; k < IN_CH; ++k) {
        // a-read: 4 distinct addrs broadcast to 16 lanes each (free);
        // b-read: 64 consecutive floats across wave -> 2-way (free).
        float4 a = *(const float4*)&As[k][ty * 4];
        float4 b = *(const float4*)&Bs[k][tx * 4];
        float av[4] = {a.x, a.y, a.z, a.w};
        float bv[4] = {b.x, b.y, b.z, b.w};
        #pragma unroll
        for (int i = 0; i < 4; ++i)
            #pragma unroll
            for (int j = 0; j < 4; ++j)
                acc[i][j] = fmaf(av[i], bv[j], acc[i][j]);
    }

    #pragma unroll
    for (int i = 0; i < 4; ++i) {
        int gnode = row0 + ty * 4 + i;
        if (gnode < N) {
            float4 v = make_float4(acc[i][0], acc[i][1], acc[i][2], acc[i][3]);
            *(float4*)&outp[(size_t)gnode * HID + tx * 4] = v;
        }
    }
}

// ---------------------------------------------------------------------------
// edge scatter: wave per edge; lane h adds xp[t][src][h]+b_rel[t][h]
// into agg[dst][h] with device-scope atomics.
// ---------------------------------------------------------------------------
__global__ __launch_bounds__(256) void edge_kernel(
    const int* __restrict__ edge_index,  // [2,E]
    const int* __restrict__ edge_type,   // [E]
    const float* __restrict__ xp,        // [8,N,64]
    const float* __restrict__ b_rel,     // [8,64]
    float* __restrict__ agg,             // [N,64]
    int E, int N)
{
    long long gid = (long long)blockIdx.x * blockDim.x + threadIdx.x;
    int e = (int)(gid >> 6);
    int h = (int)(gid & 63);
    if (e >= E) return;
    int src = edge_index[e];        // row (broadcast load, same addr all lanes)
    int dst = edge_index[E + e];    // col
    int t   = edge_type[e];
    float m = xp[((size_t)t * N + src) * HID + h] + b_rel[t * HID + h];
    atomicAdd(agg + (size_t)dst * HID + h, m);
}

// ---------------------------------------------------------------------------
// finalize: wave per node: out[n] = W_out . relu(agg[n] + b_self) + b_out
// ---------------------------------------------------------------------------
__global__ __launch_bounds__(256) void finalize_kernel(
    const float* __restrict__ agg,     // [N,64] (= x@W_self^T + sum msgs)
    const float* __restrict__ b_self,  // [64]
    const float* __restrict__ W_out,   // [64]
    const float* __restrict__ b_out,   // [1]
    float* __restrict__ out,           // [N]
    int N)
{
    long long gid = (long long)blockIdx.x * blockDim.x + threadIdx.x;
    int n = (int)(gid >> 6);
    int h = (int)(gid & 63);
    if (n >= N) return;
    float v = agg[(size_t)n * HID + h] + b_self[h];
    v = fmaxf(v, 0.f);
    float p = v * W_out[h];
    #pragma unroll
    for (int off = 32; off > 0; off >>= 1)
        p += __shfl_down(p, off, 64);
    if (h == 0) out[n] = p + b_out[0];
}

extern "C" void kernel_launch(void* const* d_in, const int* in_sizes, int n_in,
                              void* d_out, int out_size, void* d_ws, size_t ws_size,
                              hipStream_t stream)
{
    const float* x          = (const float*)d_in[0];
    const int*   edge_index = (const int*)  d_in[1];
    const int*   edge_type  = (const int*)  d_in[2];
    const float* W_rel      = (const float*)d_in[3];
    const float* b_rel      = (const float*)d_in[4];
    const float* W_self     = (const float*)d_in[5];
    const float* b_self     = (const float*)d_in[6];
    const float* W_out      = (const float*)d_in[7];
    const float* b_out      = (const float*)d_in[8];
    float* out = (float*)d_out;

    const int N = in_sizes[0] / IN_CH;   // 100000
    const int E = in_sizes[2];           // 600000

    float* xp  = (float*)d_ws;                    // [8, N, 64]  204.8 MB
    float* agg = xp + (size_t)N_REL * N * HID;    // [N, 64]      25.6 MB

    // 1) projections (also fully initializes agg via r==8 -> no memset needed)
    dim3 gA((N + BM - 1) / BM, N_REL + 1);
    proj_kernel<<<gA, 256, 0, stream>>>(x, W_rel, W_self, xp, agg, N);

    // 2) edge messages + scatter-add
    long long ethreads = (long long)E * 64;
    int eblocks = (int)((ethreads + 255) / 256);
    edge_kernel<<<eblocks, 256, 0, stream>>>(edge_index, edge_type, xp, b_rel,
                                             agg, E, N);

    // 3) relu + output projection
    long long fthreads = (long long)N * 64;
    int fblocks = (int)((fthreads + 255) / 256);
    finalize_kernel<<<fblocks, 256, 0, stream>>>(agg, b_self, W_out, b_out,
                                                 out, N);
}